// Round 4
// baseline (853.802 us; speedup 1.0000x reference)
//
#include <hip/hip_runtime.h>

typedef unsigned short ushort_t;
typedef unsigned int uint_t;
typedef _Float16 f16_t;
typedef _Float16 half2_t __attribute__((ext_vector_type(2)));

__device__ __forceinline__ float dot2(uint_t w, uint_t x, float acc) {
    return __builtin_amdgcn_fdot2(__builtin_bit_cast(half2_t, w),
                                  __builtin_bit_cast(half2_t, x), acc, false);
}
__device__ __forceinline__ ushort_t f2h_bits(float f) {
    f16_t h = (f16_t)f;
    return __builtin_bit_cast(ushort_t, h);
}
__device__ __forceinline__ float h2f(ushort_t u) {
    return (float)__builtin_bit_cast(f16_t, u);
}
__device__ __forceinline__ float sigm(float x) { return 1.0f / (1.0f + __expf(-x)); }
__device__ __forceinline__ float tanhx(float x) {
    x = fminf(fmaxf(x, -15.0f), 15.0f);
    float e = __expf(2.0f * x);
    return (e - 1.0f) / (e + 1.0f);
}

// Pack fp32 weights -> f16, transposed + grouped-by-8 along K:
// element (k, v) -> dst[((k>>3)*V + v)*8 + (k&7)]. A thread indexed by gate v
// loads 8 consecutive k's (= 4 f16-pairs) as one dwordx4. k >= KA+KB pads 0.
__global__ void pack_w(const float* __restrict__ srcA, int KA,
                       const float* __restrict__ srcB, int KB,
                       ushort_t* __restrict__ dst, int V, int Kpad)
{
    int idx = blockIdx.x * 256 + threadIdx.x;
    if (idx >= V * Kpad) return;
    int v = idx / Kpad;
    int k = idx - v * Kpad;
    float val = 0.0f;
    if (k < KA) val = srcA[v * KA + k];
    else if (k < KA + KB) val = srcB[v * KB + (k - KA)];
    dst[((k >> 3) * V + v) * 8 + (k & 7)] = f2h_bits(val);
}

// Phase A: time-LSTM with zero state == two feed-forward gated layers
// (f-gate dead). Block = 16 rows x 256 gate-units; f16 dot2 datapath.
__global__ __launch_bounds__(256) void phaseA(
    const float* __restrict__ note,
    const ushort_t* __restrict__ Wp0, const float* __restrict__ b0,
    const ushort_t* __restrict__ Wp1, const float* __restrict__ b1,
    ushort_t* __restrict__ feats)
{
    __shared__ __align__(16) uint_t x0p[28 * 16];    // [kpair][row] f16 pairs, K=56
    __shared__ __align__(16) uint_t h1p[128 * 16];   // [kpair][row], 256 units
    ushort_t* x0us = (ushort_t*)x0p;
    ushort_t* h1us = (ushort_t*)h1p;
    const int tid = threadIdx.x;
    const int row0 = blockIdx.x * 16;

    // build the 50-feature input rows (pitch_pos | pitch_class | vicinity | chord)
    for (int idx = tid; idx < 16 * 56; idx += 256) {
        int r = idx / 56;
        int c = idx - r * 56;
        int row = row0 + r;
        int b = row / 48;
        int n = row - b * 48;
        float val = 0.0f;
        if (c == 0) val = (float)n * (1.0f / 48.0f);
        else if (c < 13) val = ((n % 12) == (c - 1)) ? 1.0f : 0.0f;
        else if (c < 38) {
            int p = n + (c - 13) - 12;
            if (p >= 0 && p < 48) val = note[b * 48 + p];
        } else if (c < 50) {
            const float* nb = note + b * 48 + (c - 38) * 4;
            val = nb[0] + nb[1] + nb[2] + nb[3];
        }
        x0us[(c >> 1) * 32 + r * 2 + (c & 1)] = f2h_bits(val);
    }
    __syncthreads();

    float ai[16], ag[16], ao[16];
    float hv[16];
    {
        float bi = b0[tid], bg = b0[512 + tid], bo = b0[768 + tid];
#pragma unroll
        for (int r = 0; r < 16; ++r) { ai[r] = bi; ag[r] = bg; ao[r] = bo; }
    }
    // layer 0: K = 56 (7 k-groups of 8)
    for (int kg = 0; kg < 7; ++kg) {
        uint4 wiq = *(const uint4*)(Wp0 + (kg * 1024 + tid) * 8);
        uint4 wgq = *(const uint4*)(Wp0 + (kg * 1024 + 512 + tid) * 8);
        uint4 woq = *(const uint4*)(Wp0 + (kg * 1024 + 768 + tid) * 8);
        const uint_t* wi = (const uint_t*)&wiq;
        const uint_t* wg = (const uint_t*)&wgq;
        const uint_t* wo = (const uint_t*)&woq;
#pragma unroll
        for (int jj = 0; jj < 4; ++jj) {
            uint_t wwi = wi[jj], wwg = wg[jj], wwo = wo[jj];
            const uint4* xp = (const uint4*)&x0p[(kg * 4 + jj) * 16];
#pragma unroll
            for (int q = 0; q < 4; ++q) {
                uint4 xv = xp[q];
                ai[q*4+0] = dot2(wwi, xv.x, ai[q*4+0]); ai[q*4+1] = dot2(wwi, xv.y, ai[q*4+1]);
                ai[q*4+2] = dot2(wwi, xv.z, ai[q*4+2]); ai[q*4+3] = dot2(wwi, xv.w, ai[q*4+3]);
                ag[q*4+0] = dot2(wwg, xv.x, ag[q*4+0]); ag[q*4+1] = dot2(wwg, xv.y, ag[q*4+1]);
                ag[q*4+2] = dot2(wwg, xv.z, ag[q*4+2]); ag[q*4+3] = dot2(wwg, xv.w, ag[q*4+3]);
                ao[q*4+0] = dot2(wwo, xv.x, ao[q*4+0]); ao[q*4+1] = dot2(wwo, xv.y, ao[q*4+1]);
                ao[q*4+2] = dot2(wwo, xv.z, ao[q*4+2]); ao[q*4+3] = dot2(wwo, xv.w, ao[q*4+3]);
            }
        }
    }
#pragma unroll
    for (int r = 0; r < 16; ++r) {
        float c = sigm(ai[r]) * tanhx(ag[r]);
        hv[r] = sigm(ao[r]) * tanhx(c);
    }
    // packed f16 h1 write; r swizzled by unit-pair to spread banks
#pragma unroll
    for (int jj = 0; jj < 16; ++jj) {
        int r = (jj + (tid >> 1)) & 15;
        h1us[(tid >> 1) * 32 + r * 2 + (tid & 1)] = f2h_bits(hv[r]);
    }
    __syncthreads();

    {
        float bi = b1[tid], bg = b1[512 + tid], bo = b1[768 + tid];
#pragma unroll
        for (int r = 0; r < 16; ++r) { ai[r] = bi; ag[r] = bg; ao[r] = bo; }
    }
    // layer 1: K = 256 (32 k-groups)
    for (int kg = 0; kg < 32; ++kg) {
        uint4 wiq = *(const uint4*)(Wp1 + (kg * 1024 + tid) * 8);
        uint4 wgq = *(const uint4*)(Wp1 + (kg * 1024 + 512 + tid) * 8);
        uint4 woq = *(const uint4*)(Wp1 + (kg * 1024 + 768 + tid) * 8);
        const uint_t* wi = (const uint_t*)&wiq;
        const uint_t* wg = (const uint_t*)&wgq;
        const uint_t* wo = (const uint_t*)&woq;
#pragma unroll
        for (int jj = 0; jj < 4; ++jj) {
            uint_t wwi = wi[jj], wwg = wg[jj], wwo = wo[jj];
            const uint4* xp = (const uint4*)&h1p[(kg * 4 + jj) * 16];
#pragma unroll
            for (int q = 0; q < 4; ++q) {
                uint4 xv = xp[q];
                ai[q*4+0] = dot2(wwi, xv.x, ai[q*4+0]); ai[q*4+1] = dot2(wwi, xv.y, ai[q*4+1]);
                ai[q*4+2] = dot2(wwi, xv.z, ai[q*4+2]); ai[q*4+3] = dot2(wwi, xv.w, ai[q*4+3]);
                ag[q*4+0] = dot2(wwg, xv.x, ag[q*4+0]); ag[q*4+1] = dot2(wwg, xv.y, ag[q*4+1]);
                ag[q*4+2] = dot2(wwg, xv.z, ag[q*4+2]); ag[q*4+3] = dot2(wwg, xv.w, ag[q*4+3]);
                ao[q*4+0] = dot2(wwo, xv.x, ao[q*4+0]); ao[q*4+1] = dot2(wwo, xv.y, ao[q*4+1]);
                ao[q*4+2] = dot2(wwo, xv.z, ao[q*4+2]); ao[q*4+3] = dot2(wwo, xv.w, ao[q*4+3]);
            }
        }
    }
#pragma unroll
    for (int r = 0; r < 16; ++r) {
        float c = sigm(ai[r]) * tanhx(ag[r]);
        float h2 = sigm(ao[r]) * tanhx(c);
        feats[(size_t)(row0 + r) * 256 + tid] = f2h_bits(h2);  // f16 bits
    }
}

// G1 precompute: G1[row, 512] = bias0 + Wih0 @ [feats(256); cond(1); pad]
// — the non-recurrent part of phaseB layer-1. Block = 16 rows x 256 threads,
// each thread computes gates (tid, tid+256). x in LDS as [row][pair].
__global__ __launch_bounds__(256) void g1k(
    const ushort_t* __restrict__ feats, const float* __restrict__ targets,
    const ushort_t* __restrict__ Wx, const float* __restrict__ b0,
    ushort_t* __restrict__ G1)
{
    __shared__ __align__(16) uint_t xg[16 * 132];   // [row][pair], K=264 padded
    const int tid = threadIdx.x;
    const int row0 = blockIdx.x * 16;

    // stage feats pairs: coalesced global, conflict-free LDS (contiguous p)
    for (int idx = tid; idx < 2048; idx += 256) {
        int p = idx & 127;
        int r = idx >> 7;
        xg[r * 132 + p] = *(const uint_t*)(feats + (size_t)(row0 + r) * 256 + 2 * p);
    }
    // pairs 128..131: (cond,0) + zero pad
    if (tid < 64) {
        int r = tid >> 2;
        int pp = tid & 3;
        uint_t v = 0;
        if (pp == 0) {
            int row = row0 + r;
            int b = row / 48;
            int t = row - b * 48;
            float c = (t > 0) ? targets[b * 48 + t - 1] : 0.0f;
            v = (uint_t)f2h_bits(c);
        }
        xg[r * 132 + 128 + pp] = v;
    }
    __syncthreads();

    float accA[16], accB[16];
    {
        float bA = b0[tid], bB = b0[tid + 256];
#pragma unroll
        for (int r = 0; r < 16; ++r) { accA[r] = bA; accB[r] = bB; }
    }
    const uint4* wpA = (const uint4*)Wx + tid;
    const uint4* wpB = wpA + 256;
    uint4 wA = wpA[0], wB = wpB[0];
    for (int kg = 0; kg < 33; ++kg) {
        uint4 wAn = (kg < 32) ? wpA[(kg + 1) * 512] : wA;
        uint4 wBn = (kg < 32) ? wpB[(kg + 1) * 512] : wB;
        const uint_t* wua = (const uint_t*)&wA;
        const uint_t* wub = (const uint_t*)&wB;
#pragma unroll
        for (int r = 0; r < 16; ++r) {
            uint4 xr = *(const uint4*)&xg[r * 132 + kg * 4];
            const uint_t* xu = (const uint_t*)&xr;
#pragma unroll
            for (int jj = 0; jj < 4; ++jj) {
                accA[r] = dot2(wua[jj], xu[jj], accA[r]);
                accB[r] = dot2(wub[jj], xu[jj], accB[r]);
            }
        }
        wA = wAn; wB = wBn;
    }
#pragma unroll
    for (int r = 0; r < 16; ++r) {
        G1[(size_t)(row0 + r) * 512 + tid]       = f2h_bits(accA[r]);
        G1[(size_t)(row0 + r) * 512 + tid + 256] = f2h_bits(accB[r]);
    }
}

// Phase B: 48-step 2-layer LSTM scan, 4 batch rows per persistent block.
// Layer-1 input part precomputed (G1); Whh0 resident in LDS (131 kB);
// layer-2 weights streamed from L2 with 2-deep prefetch. 4 barriers/step.
__global__ __launch_bounds__(512) void phaseB(
    const ushort_t* __restrict__ G1,
    const ushort_t* __restrict__ N0h,
    const ushort_t* __restrict__ N1p, const float* __restrict__ nb1,
    const float* __restrict__ outW, const float* __restrict__ outb,
    float* __restrict__ out)
{
    __shared__ __align__(16) uint4 w1s[16 * 512];    // Whh0 packed: [kg][gate][quad] = 131072 B
    __shared__ __align__(16) uint_t h1p[4 * 64];     // [row][pair] h1
    __shared__ __align__(16) uint_t x2s[4 * 128];    // [row][pair] h1|h2
    __shared__ __align__(16) float g_lds[512 * 4];   // [gate][row]
    __shared__ __align__(16) uint_t owp[64];
    const int tid = threadIdx.x;
    const int r0 = blockIdx.x * 4;

    // one-time: Whh0 -> LDS, zero states, out weights
    {
        const uint4* src = (const uint4*)N0h;
        for (int i = tid; i < 16 * 512; i += 512) w1s[i] = src[i];
    }
    for (int i = tid; i < 4 * 64; i += 512) h1p[i] = 0;
    if (tid < 4 * 128) x2s[tid] = 0;
    if (tid < 64) {
        uint_t lo = f2h_bits(outW[2 * tid]);
        uint_t hi = f2h_bits(outW[2 * tid + 1]);
        owp[tid] = lo | (hi << 16);
    }
    const float bias1 = nb1[tid];
    const float ob = outb[0];
    const int unit = tid >> 2;
    const int rr = tid & 3;
    ushort_t* h1us = (ushort_t*)h1p;
    ushort_t* x2us = (ushort_t*)x2s;
    float c1 = 0.0f, c2 = 0.0f;
    __syncthreads();

    const uint4* wp2 = (const uint4*)N1p + tid;

    for (int t = 0; t < 48; ++t) {
        // early loads: G1 (this thread's gate, 4 rows) + layer-2 weight prefetch
        const ushort_t* g1p = G1 + ((size_t)r0 * 48 + t) * 512 + tid;
        ushort_t u0 = g1p[0];
        ushort_t u1 = g1p[48 * 512];
        ushort_t u2 = g1p[2 * 48 * 512];
        ushort_t u3 = g1p[3 * 48 * 512];
        uint4 wq0 = wp2[0];
        uint4 wq1 = wp2[512];

        // layer-1 gates: a = G1 + Whh0 @ h1_prev, K=128 (16 kg), W from LDS
        {
            float a0 = h2f(u0), a1 = h2f(u1), a2 = h2f(u2), a3 = h2f(u3);
            for (int kg = 0; kg < 16; ++kg) {
                uint4 w = w1s[kg * 512 + tid];
                const uint_t* wu = (const uint_t*)&w;
                uint4 x0 = *(const uint4*)&h1p[kg * 4];
                uint4 x1 = *(const uint4*)&h1p[64 + kg * 4];
                uint4 x2 = *(const uint4*)&h1p[128 + kg * 4];
                uint4 x3 = *(const uint4*)&h1p[192 + kg * 4];
                const uint_t* x0u = (const uint_t*)&x0;
                const uint_t* x1u = (const uint_t*)&x1;
                const uint_t* x2u = (const uint_t*)&x2;
                const uint_t* x3u = (const uint_t*)&x3;
#pragma unroll
                for (int jj = 0; jj < 4; ++jj) {
                    a0 = dot2(wu[jj], x0u[jj], a0);
                    a1 = dot2(wu[jj], x1u[jj], a1);
                    a2 = dot2(wu[jj], x2u[jj], a2);
                    a3 = dot2(wu[jj], x3u[jj], a3);
                }
            }
            *(float4*)&g_lds[tid * 4] = make_float4(a0, a1, a2, a3);
        }
        __syncthreads();
        // layer-1 elementwise
        {
            float gi = g_lds[unit * 4 + rr];
            float gf = g_lds[(128 + unit) * 4 + rr];
            float gg = g_lds[(256 + unit) * 4 + rr];
            float go = g_lds[(384 + unit) * 4 + rr];
            c1 = sigm(gf) * c1 + sigm(gi) * tanhx(gg);
            float h1 = sigm(go) * tanhx(c1);
            ushort_t hb = f2h_bits(h1);
            h1us[(rr * 64 + (unit >> 1)) * 2 + (unit & 1)] = hb;
            x2us[(rr * 128 + (unit >> 1)) * 2 + (unit & 1)] = hb;
        }
        __syncthreads();
        // layer-2 gates: K=256 (32 kg), weights streamed, 2-deep prefetch
        {
            float a0 = bias1, a1 = bias1, a2 = bias1, a3 = bias1;
            for (int kg = 0; kg < 32; ++kg) {
                uint4 wn = (kg < 30) ? wp2[(kg + 2) * 512] : wq1;
                const uint_t* wu = (const uint_t*)&wq0;
                uint4 x0 = *(const uint4*)&x2s[kg * 4];
                uint4 x1 = *(const uint4*)&x2s[128 + kg * 4];
                uint4 x2 = *(const uint4*)&x2s[256 + kg * 4];
                uint4 x3 = *(const uint4*)&x2s[384 + kg * 4];
                const uint_t* x0u = (const uint_t*)&x0;
                const uint_t* x1u = (const uint_t*)&x1;
                const uint_t* x2u = (const uint_t*)&x2;
                const uint_t* x3u = (const uint_t*)&x3;
#pragma unroll
                for (int jj = 0; jj < 4; ++jj) {
                    a0 = dot2(wu[jj], x0u[jj], a0);
                    a1 = dot2(wu[jj], x1u[jj], a1);
                    a2 = dot2(wu[jj], x2u[jj], a2);
                    a3 = dot2(wu[jj], x3u[jj], a3);
                }
                wq0 = wq1; wq1 = wn;
            }
            *(float4*)&g_lds[tid * 4] = make_float4(a0, a1, a2, a3);
        }
        __syncthreads();
        // layer-2 elementwise
        {
            float gi = g_lds[unit * 4 + rr];
            float gf = g_lds[(128 + unit) * 4 + rr];
            float gg = g_lds[(256 + unit) * 4 + rr];
            float go = g_lds[(384 + unit) * 4 + rr];
            c2 = sigm(gf) * c2 + sigm(gi) * tanhx(gg);
            float h2 = sigm(go) * tanhx(c2);
            x2us[(rr * 128 + 64 + (unit >> 1)) * 2 + (unit & 1)] = f2h_bits(h2);
        }
        __syncthreads();
        // output head: dot2 over h2 pairs, wave-per-row shuffle reduce
        if (tid < 256) {
            int r = tid >> 6;
            int l = tid & 63;
            float p = dot2(owp[l], x2s[r * 128 + 64 + l], 0.0f);
#pragma unroll
            for (int off = 32; off > 0; off >>= 1) p += __shfl_down(p, off, 64);
            if (l == 0) out[(r0 + r) * 48 + t] = sigm(p + ob);
        }
    }
}

extern "C" void kernel_launch(void* const* d_in, const int* in_sizes, int n_in,
                              void* d_out, int out_size, void* d_ws, size_t ws_size,
                              hipStream_t stream)
{
    const float* note  = (const float*)d_in[0];
    const float* targ  = (const float*)d_in[1];
    const float* tWih0 = (const float*)d_in[2];
    const float* tb0   = (const float*)d_in[4];
    const float* tWih1 = (const float*)d_in[5];
    const float* tb1   = (const float*)d_in[7];
    const float* nWih0 = (const float*)d_in[8];
    const float* nWhh0 = (const float*)d_in[9];
    const float* nb0   = (const float*)d_in[10];
    const float* nWih1 = (const float*)d_in[11];
    const float* nWhh1 = (const float*)d_in[12];
    const float* nb1   = (const float*)d_in[13];
    const float* outW  = (const float*)d_in[14];
    const float* outb  = (const float*)d_in[15];

    char* ws = (char*)d_ws;
    ushort_t* feats = (ushort_t*)(ws);               // 49152*256 f16 = 25165824 B
    ushort_t* G1    = (ushort_t*)(ws + 25165824);    // 49152*512 f16 = 50331648 B
    ushort_t* W0p   = (ushort_t*)(ws + 75497472);    // 56*1024   f16 = 114688 B
    ushort_t* W1p   = (ushort_t*)(ws + 75612160);    // 256*1024  f16 = 524288 B
    ushort_t* N0x   = (ushort_t*)(ws + 76136448);    // 264*512   f16 = 270336 B
    ushort_t* N0h   = (ushort_t*)(ws + 76406784);    // 128*512   f16 = 131072 B
    ushort_t* N1p   = (ushort_t*)(ws + 76537856);    // 256*512   f16 = 262144 B

    pack_w<<<(1024 * 56 + 255) / 256, 256, 0, stream>>>(tWih0, 50, (const float*)0, 0, W0p, 1024, 56);
    pack_w<<<(1024 * 256 + 255) / 256, 256, 0, stream>>>(tWih1, 256, (const float*)0, 0, W1p, 1024, 256);
    pack_w<<<(512 * 264 + 255) / 256, 256, 0, stream>>>(nWih0, 257, (const float*)0, 0, N0x, 512, 264);
    pack_w<<<(512 * 128 + 255) / 256, 256, 0, stream>>>(nWhh0, 128, (const float*)0, 0, N0h, 512, 128);
    pack_w<<<(512 * 256 + 255) / 256, 256, 0, stream>>>(nWih1, 128, nWhh1, 128, N1p, 512, 256);

    phaseA<<<3072, 256, 0, stream>>>(note, W0p, tb0, W1p, tb1, feats);
    g1k<<<3072, 256, 0, stream>>>(feats, targ, N0x, nb0, G1);
    phaseB<<<256, 512, 0, stream>>>(G1, N0h, N1p, nb1, outW, outb, (float*)d_out);
}

// Round 5
// 706.577 us; speedup vs baseline: 1.2084x; 1.2084x over previous
//
#include <hip/hip_runtime.h>

typedef unsigned short ushort_t;
typedef unsigned int uint_t;
typedef _Float16 f16_t;
typedef _Float16 half2_t __attribute__((ext_vector_type(2)));
typedef _Float16 half8_t __attribute__((ext_vector_type(8)));
typedef float floatx4 __attribute__((ext_vector_type(4)));

__device__ __forceinline__ float dot2(uint_t w, uint_t x, float acc) {
    return __builtin_amdgcn_fdot2(__builtin_bit_cast(half2_t, w),
                                  __builtin_bit_cast(half2_t, x), acc, false);
}
__device__ __forceinline__ ushort_t f2h_bits(float f) {
    f16_t h = (f16_t)f;
    return __builtin_bit_cast(ushort_t, h);
}
__device__ __forceinline__ float h2f(ushort_t u) {
    return (float)__builtin_bit_cast(f16_t, u);
}
__device__ __forceinline__ float sigm(float x) { return 1.0f / (1.0f + __expf(-x)); }
__device__ __forceinline__ float tanhx(float x) {
    x = fminf(fmaxf(x, -15.0f), 15.0f);
    float e = __expf(2.0f * x);
    return (e - 1.0f) / (e + 1.0f);
}

// Pack fp32 weights -> f16, transposed + grouped-by-8 along K (dot2 kernels):
// element (k, v) -> dst[((k>>3)*V + v)*8 + (k&7)].
__global__ void pack_w(const float* __restrict__ srcA, int KA,
                       const float* __restrict__ srcB, int KB,
                       ushort_t* __restrict__ dst, int V, int Kpad)
{
    int idx = blockIdx.x * 256 + threadIdx.x;
    if (idx >= V * Kpad) return;
    int v = idx / Kpad;
    int k = idx - v * Kpad;
    float val = 0.0f;
    if (k < KA) val = srcA[v * KA + k];
    else if (k < KA + KB) val = srcB[v * KB + (k - KA)];
    dst[((k >> 3) * V + v) * 8 + (k & 7)] = f2h_bits(val);
}

// Pack fp32 weights -> f16 MFMA B-fragment layout (V = 512 gates):
// B[k][n] for lane(n=l&15 within tile, q=l>>4): dst[((kt*512+v)*4+q)*8+j],
// k = kt*32 + q*8 + j. One b128 per lane per (nt,kt) fragment.
__global__ void pack_wmf(const float* __restrict__ srcA, int KA,
                         const float* __restrict__ srcB, int KB,
                         ushort_t* __restrict__ dst, int K)
{
    int idx = blockIdx.x * 256 + threadIdx.x;
    if (idx >= 512 * K) return;
    int v = idx / K;
    int k = idx - v * K;
    float val = (k < KA) ? srcA[v * KA + k] : srcB[v * KB + (k - KA)];
    int kt = k >> 5, q = (k >> 3) & 3, j = k & 7;
    dst[((kt * 512 + v) * 4 + q) * 8 + j] = f2h_bits(val);
}

// Phase A: time-LSTM with zero state == two feed-forward gated layers
// (f-gate dead). Block = 16 rows x 256 gate-units; f16 dot2 datapath.
__global__ __launch_bounds__(256) void phaseA(
    const float* __restrict__ note,
    const ushort_t* __restrict__ Wp0, const float* __restrict__ b0,
    const ushort_t* __restrict__ Wp1, const float* __restrict__ b1,
    ushort_t* __restrict__ feats)
{
    __shared__ __align__(16) uint_t x0p[28 * 16];
    __shared__ __align__(16) uint_t h1p[128 * 16];
    ushort_t* x0us = (ushort_t*)x0p;
    ushort_t* h1us = (ushort_t*)h1p;
    const int tid = threadIdx.x;
    const int row0 = blockIdx.x * 16;

    for (int idx = tid; idx < 16 * 56; idx += 256) {
        int r = idx / 56;
        int c = idx - r * 56;
        int row = row0 + r;
        int b = row / 48;
        int n = row - b * 48;
        float val = 0.0f;
        if (c == 0) val = (float)n * (1.0f / 48.0f);
        else if (c < 13) val = ((n % 12) == (c - 1)) ? 1.0f : 0.0f;
        else if (c < 38) {
            int p = n + (c - 13) - 12;
            if (p >= 0 && p < 48) val = note[b * 48 + p];
        } else if (c < 50) {
            const float* nb = note + b * 48 + (c - 38) * 4;
            val = nb[0] + nb[1] + nb[2] + nb[3];
        }
        x0us[(c >> 1) * 32 + r * 2 + (c & 1)] = f2h_bits(val);
    }
    __syncthreads();

    float ai[16], ag[16], ao[16];
    float hv[16];
    {
        float bi = b0[tid], bg = b0[512 + tid], bo = b0[768 + tid];
#pragma unroll
        for (int r = 0; r < 16; ++r) { ai[r] = bi; ag[r] = bg; ao[r] = bo; }
    }
    for (int kg = 0; kg < 7; ++kg) {
        uint4 wiq = *(const uint4*)(Wp0 + (kg * 1024 + tid) * 8);
        uint4 wgq = *(const uint4*)(Wp0 + (kg * 1024 + 512 + tid) * 8);
        uint4 woq = *(const uint4*)(Wp0 + (kg * 1024 + 768 + tid) * 8);
        const uint_t* wi = (const uint_t*)&wiq;
        const uint_t* wg = (const uint_t*)&wgq;
        const uint_t* wo = (const uint_t*)&woq;
#pragma unroll
        for (int jj = 0; jj < 4; ++jj) {
            uint_t wwi = wi[jj], wwg = wg[jj], wwo = wo[jj];
            const uint4* xp = (const uint4*)&x0p[(kg * 4 + jj) * 16];
#pragma unroll
            for (int q = 0; q < 4; ++q) {
                uint4 xv = xp[q];
                ai[q*4+0] = dot2(wwi, xv.x, ai[q*4+0]); ai[q*4+1] = dot2(wwi, xv.y, ai[q*4+1]);
                ai[q*4+2] = dot2(wwi, xv.z, ai[q*4+2]); ai[q*4+3] = dot2(wwi, xv.w, ai[q*4+3]);
                ag[q*4+0] = dot2(wwg, xv.x, ag[q*4+0]); ag[q*4+1] = dot2(wwg, xv.y, ag[q*4+1]);
                ag[q*4+2] = dot2(wwg, xv.z, ag[q*4+2]); ag[q*4+3] = dot2(wwg, xv.w, ag[q*4+3]);
                ao[q*4+0] = dot2(wwo, xv.x, ao[q*4+0]); ao[q*4+1] = dot2(wwo, xv.y, ao[q*4+1]);
                ao[q*4+2] = dot2(wwo, xv.z, ao[q*4+2]); ao[q*4+3] = dot2(wwo, xv.w, ao[q*4+3]);
            }
        }
    }
#pragma unroll
    for (int r = 0; r < 16; ++r) {
        float c = sigm(ai[r]) * tanhx(ag[r]);
        hv[r] = sigm(ao[r]) * tanhx(c);
    }
#pragma unroll
    for (int jj = 0; jj < 16; ++jj) {
        int r = (jj + (tid >> 1)) & 15;
        h1us[(tid >> 1) * 32 + r * 2 + (tid & 1)] = f2h_bits(hv[r]);
    }
    __syncthreads();

    {
        float bi = b1[tid], bg = b1[512 + tid], bo = b1[768 + tid];
#pragma unroll
        for (int r = 0; r < 16; ++r) { ai[r] = bi; ag[r] = bg; ao[r] = bo; }
    }
    for (int kg = 0; kg < 32; ++kg) {
        uint4 wiq = *(const uint4*)(Wp1 + (kg * 1024 + tid) * 8);
        uint4 wgq = *(const uint4*)(Wp1 + (kg * 1024 + 512 + tid) * 8);
        uint4 woq = *(const uint4*)(Wp1 + (kg * 1024 + 768 + tid) * 8);
        const uint_t* wi = (const uint_t*)&wiq;
        const uint_t* wg = (const uint_t*)&wgq;
        const uint_t* wo = (const uint_t*)&woq;
#pragma unroll
        for (int jj = 0; jj < 4; ++jj) {
            uint_t wwi = wi[jj], wwg = wg[jj], wwo = wo[jj];
            const uint4* xp = (const uint4*)&h1p[(kg * 4 + jj) * 16];
#pragma unroll
            for (int q = 0; q < 4; ++q) {
                uint4 xv = xp[q];
                ai[q*4+0] = dot2(wwi, xv.x, ai[q*4+0]); ai[q*4+1] = dot2(wwi, xv.y, ai[q*4+1]);
                ai[q*4+2] = dot2(wwi, xv.z, ai[q*4+2]); ai[q*4+3] = dot2(wwi, xv.w, ai[q*4+3]);
                ag[q*4+0] = dot2(wwg, xv.x, ag[q*4+0]); ag[q*4+1] = dot2(wwg, xv.y, ag[q*4+1]);
                ag[q*4+2] = dot2(wwg, xv.z, ag[q*4+2]); ag[q*4+3] = dot2(wwg, xv.w, ag[q*4+3]);
                ao[q*4+0] = dot2(wwo, xv.x, ao[q*4+0]); ao[q*4+1] = dot2(wwo, xv.y, ao[q*4+1]);
                ao[q*4+2] = dot2(wwo, xv.z, ao[q*4+2]); ao[q*4+3] = dot2(wwo, xv.w, ao[q*4+3]);
            }
        }
    }
#pragma unroll
    for (int r = 0; r < 16; ++r) {
        float c = sigm(ai[r]) * tanhx(ag[r]);
        float h2 = sigm(ao[r]) * tanhx(c);
        feats[(size_t)(row0 + r) * 256 + tid] = f2h_bits(h2);
    }
}

// G1 precompute: G1[row, 512] = bias0 + Wih0 @ [feats(256); cond(1); pad]
__global__ __launch_bounds__(256) void g1k(
    const ushort_t* __restrict__ feats, const float* __restrict__ targets,
    const ushort_t* __restrict__ Wx, const float* __restrict__ b0,
    ushort_t* __restrict__ G1)
{
    __shared__ __align__(16) uint_t xg[16 * 132];
    const int tid = threadIdx.x;
    const int row0 = blockIdx.x * 16;

    for (int idx = tid; idx < 2048; idx += 256) {
        int p = idx & 127;
        int r = idx >> 7;
        xg[r * 132 + p] = *(const uint_t*)(feats + (size_t)(row0 + r) * 256 + 2 * p);
    }
    if (tid < 64) {
        int r = tid >> 2;
        int pp = tid & 3;
        uint_t v = 0;
        if (pp == 0) {
            int row = row0 + r;
            int b = row / 48;
            int t = row - b * 48;
            float c = (t > 0) ? targets[b * 48 + t - 1] : 0.0f;
            v = (uint_t)f2h_bits(c);
        }
        xg[r * 132 + 128 + pp] = v;
    }
    __syncthreads();

    float accA[16], accB[16];
    {
        float bA = b0[tid], bB = b0[tid + 256];
#pragma unroll
        for (int r = 0; r < 16; ++r) { accA[r] = bA; accB[r] = bB; }
    }
    const uint4* wpA = (const uint4*)Wx + tid;
    const uint4* wpB = wpA + 256;
    uint4 wA = wpA[0], wB = wpB[0];
    for (int kg = 0; kg < 33; ++kg) {
        uint4 wAn = (kg < 32) ? wpA[(kg + 1) * 512] : wA;
        uint4 wBn = (kg < 32) ? wpB[(kg + 1) * 512] : wB;
        const uint_t* wua = (const uint_t*)&wA;
        const uint_t* wub = (const uint_t*)&wB;
#pragma unroll
        for (int r = 0; r < 16; ++r) {
            uint4 xr = *(const uint4*)&xg[r * 132 + kg * 4];
            const uint_t* xu = (const uint_t*)&xr;
#pragma unroll
            for (int jj = 0; jj < 4; ++jj) {
                accA[r] = dot2(wua[jj], xu[jj], accA[r]);
                accB[r] = dot2(wub[jj], xu[jj], accB[r]);
            }
        }
        wA = wAn; wB = wBn;
    }
#pragma unroll
    for (int r = 0; r < 16; ++r) {
        G1[(size_t)(row0 + r) * 512 + tid]       = f2h_bits(accA[r]);
        G1[(size_t)(row0 + r) * 512 + tid + 256] = f2h_bits(accB[r]);
    }
}

// Phase B (MFMA): 48-step 2-layer LSTM scan. 64 blocks x 16 batch rows,
// 8 waves each owning a 64-gate N-slice (4 MFMA 16x16x32 f16 tiles).
// L1 Whh0 B-frags resident in registers; L2 weights streamed from L2$.
// h1|h2 state in one XOR-swizzled LDS A-layout buffer xA[16][256].
__global__ __launch_bounds__(512) void phaseB(
    const ushort_t* __restrict__ G1,
    const ushort_t* __restrict__ N0m,
    const ushort_t* __restrict__ N1m, const float* __restrict__ nb1,
    const float* __restrict__ outW, const float* __restrict__ outb,
    float* __restrict__ out)
{
    __shared__ __align__(16) ushort_t xA[16 * 256];  // [m][swizzled k]
    __shared__ __align__(16) float gS[512 * 16];     // [n][q^swz][reg]
    __shared__ __align__(16) uint_t owp[64];

    const int tid = threadIdx.x;
    const int wv  = tid >> 6;
    const int l   = tid & 63;
    const int l16 = l & 15;
    const int q   = l >> 4;
    const int r0  = blockIdx.x * 16;

    for (int i = tid; i < 16 * 256 / 8; i += 512) ((uint4*)xA)[i] = make_uint4(0, 0, 0, 0);
    if (tid < 64) {
        uint_t lo = f2h_bits(outW[2 * tid]);
        uint_t hi = f2h_bits(outW[2 * tid + 1]);
        owp[tid] = lo | (hi << 16);
    }
    const int eu = tid >> 2;      // elementwise: unit 0..127
    const int erg = tid & 3;      // row group (4 rows each)
    const float eb1i = nb1[eu], eb1f = nb1[128 + eu], eb1g = nb1[256 + eu], eb1o = nb1[384 + eu];
    const float ob = outb[0];
    float c1[4] = {0, 0, 0, 0}, c2[4] = {0, 0, 0, 0};

    // resident L1 B-frags: [nt][kt]
    half8_t B1[4][4];
#pragma unroll
    for (int nt = 0; nt < 4; ++nt) {
        int n = wv * 64 + nt * 16 + l16;
#pragma unroll
        for (int kt = 0; kt < 4; ++kt)
            B1[nt][kt] = __builtin_bit_cast(half8_t,
                *(const uint4*)(N0m + ((kt * 512 + n) * 4 + q) * 8));
    }
    __syncthreads();

    const int mq = q * 4;
    const int esw = (erg ^ (eu & 3)) << 2;   // gS read swizzle (same for all 4 gates)

    for (int t = 0; t < 48; ++t) {
        // G1 for this lane's D elements (folded at D-write)
        ushort_t g1v[16];
#pragma unroll
        for (int nt = 0; nt < 4; ++nt)
#pragma unroll
            for (int rg = 0; rg < 4; ++rg)
                g1v[nt * 4 + rg] =
                    G1[((size_t)(r0 + mq + rg) * 48 + t) * 512 + wv * 64 + nt * 16 + l16];

        // L1 MFMA: D = h1_prev @ Whh0^T  (A from xA k<128, B resident)
        floatx4 acc[4] = {};
#pragma unroll
        for (int kt = 0; kt < 4; ++kt) {
            int kb = kt * 4 + q;
            int kbp = (kb ^ l16) & 15;
            half8_t a = __builtin_bit_cast(half8_t, *(const uint4*)&xA[l16 * 256 + kbp * 8]);
#pragma unroll
            for (int nt = 0; nt < 4; ++nt)
                acc[nt] = __builtin_amdgcn_mfma_f32_16x16x32_f16(a, B1[nt][kt], acc[nt], 0, 0, 0);
        }
#pragma unroll
        for (int nt = 0; nt < 4; ++nt) {
            int n = wv * 64 + nt * 16 + l16;
            float4 w4 = make_float4(acc[nt].x + h2f(g1v[nt * 4 + 0]),
                                    acc[nt].y + h2f(g1v[nt * 4 + 1]),
                                    acc[nt].z + h2f(g1v[nt * 4 + 2]),
                                    acc[nt].w + h2f(g1v[nt * 4 + 3]));
            *(float4*)&gS[n * 16 + ((q ^ (n & 3)) << 2)] = w4;
        }
        __syncthreads();

        // E1: layer-1 LSTM elementwise; write h1 -> xA k=eu (swizzled)
        {
            float4 gi = *(const float4*)&gS[eu * 16 + esw];
            float4 gf = *(const float4*)&gS[(128 + eu) * 16 + esw];
            float4 gg = *(const float4*)&gS[(256 + eu) * 16 + esw];
            float4 go = *(const float4*)&gS[(384 + eu) * 16 + esw];
            const float* gip = (const float*)&gi;
            const float* gfp = (const float*)&gf;
            const float* ggp = (const float*)&gg;
            const float* gop = (const float*)&go;
            int kb = eu >> 3, j = eu & 7;
#pragma unroll
            for (int r = 0; r < 4; ++r) {
                int m = erg * 4 + r;
                c1[r] = sigm(gfp[r]) * c1[r] + sigm(gip[r]) * tanhx(ggp[r]);
                float h1 = sigm(gop[r]) * tanhx(c1[r]);
                xA[m * 256 + ((kb ^ m) & 15) * 8 + j] = f2h_bits(h1);
            }
        }
        __syncthreads();

        // L2 MFMA: K=256 (A = [h1;h2] from xA, B streamed, 2-slot pipeline)
        floatx4 acc2[4] = {};
        half8_t Bs[2][4];
#pragma unroll
        for (int s = 0; s < 2; ++s)
#pragma unroll
            for (int nt = 0; nt < 4; ++nt) {
                int n = wv * 64 + nt * 16 + l16;
                Bs[s][nt] = __builtin_bit_cast(half8_t,
                    *(const uint4*)(N1m + ((s * 512 + n) * 4 + q) * 8));
            }
#pragma unroll
        for (int kt = 0; kt < 8; ++kt) {
            int kb = kt * 4 + q;
            int kbp = (kb & 16) | ((kb ^ l16) & 15);
            half8_t a = __builtin_bit_cast(half8_t, *(const uint4*)&xA[l16 * 256 + kbp * 8]);
#pragma unroll
            for (int nt = 0; nt < 4; ++nt)
                acc2[nt] = __builtin_amdgcn_mfma_f32_16x16x32_f16(a, Bs[kt & 1][nt], acc2[nt], 0, 0, 0);
            if (kt < 6) {
#pragma unroll
                for (int nt = 0; nt < 4; ++nt) {
                    int n = wv * 64 + nt * 16 + l16;
                    Bs[kt & 1][nt] = __builtin_bit_cast(half8_t,
                        *(const uint4*)(N1m + (((kt + 2) * 512 + n) * 4 + q) * 8));
                }
            }
        }
#pragma unroll
        for (int nt = 0; nt < 4; ++nt) {
            int n = wv * 64 + nt * 16 + l16;
            *(float4*)&gS[n * 16 + ((q ^ (n & 3)) << 2)] =
                make_float4(acc2[nt].x, acc2[nt].y, acc2[nt].z, acc2[nt].w);
        }
        __syncthreads();

        // E2: layer-2 LSTM elementwise; write h2 -> xA k=128+eu (swizzled)
        {
            float4 gi = *(const float4*)&gS[eu * 16 + esw];
            float4 gf = *(const float4*)&gS[(128 + eu) * 16 + esw];
            float4 gg = *(const float4*)&gS[(256 + eu) * 16 + esw];
            float4 go = *(const float4*)&gS[(384 + eu) * 16 + esw];
            const float* gip = (const float*)&gi;
            const float* gfp = (const float*)&gf;
            const float* ggp = (const float*)&gg;
            const float* gop = (const float*)&go;
            int kb = eu >> 3, j = eu & 7;
#pragma unroll
            for (int r = 0; r < 4; ++r) {
                int m = erg * 4 + r;
                c2[r] = sigm(gfp[r] + eb1f) * c2[r] + sigm(gip[r] + eb1i) * tanhx(ggp[r] + eb1g);
                float h2 = sigm(gop[r] + eb1o) * tanhx(c2[r]);
                xA[m * 256 + (16 | ((kb ^ m) & 15)) * 8 + j] = f2h_bits(h2);
            }
        }
        __syncthreads();

        // output head: 32 lanes per row, dot2 + shuffle reduce (width 32)
        {
            int m = tid >> 5, hl = tid & 31;
            int kbp = 16 | (((hl >> 1) ^ m) & 15);
            uint2 xv = *(const uint2*)&xA[m * 256 + kbp * 8 + (hl & 1) * 4];
            float p = dot2(owp[hl * 2], xv.x, 0.0f);
            p = dot2(owp[hl * 2 + 1], xv.y, p);
#pragma unroll
            for (int off = 16; off > 0; off >>= 1) p += __shfl_down(p, off, 32);
            if (hl == 0) out[(r0 + m) * 48 + t] = sigm(p + ob);
        }
    }
}

extern "C" void kernel_launch(void* const* d_in, const int* in_sizes, int n_in,
                              void* d_out, int out_size, void* d_ws, size_t ws_size,
                              hipStream_t stream)
{
    const float* note  = (const float*)d_in[0];
    const float* targ  = (const float*)d_in[1];
    const float* tWih0 = (const float*)d_in[2];
    const float* tb0   = (const float*)d_in[4];
    const float* tWih1 = (const float*)d_in[5];
    const float* tb1   = (const float*)d_in[7];
    const float* nWih0 = (const float*)d_in[8];
    const float* nWhh0 = (const float*)d_in[9];
    const float* nb0   = (const float*)d_in[10];
    const float* nWih1 = (const float*)d_in[11];
    const float* nWhh1 = (const float*)d_in[12];
    const float* nb1   = (const float*)d_in[13];
    const float* outW  = (const float*)d_in[14];
    const float* outb  = (const float*)d_in[15];

    char* ws = (char*)d_ws;
    ushort_t* feats = (ushort_t*)(ws);               // 49152*256 f16 = 25165824 B
    ushort_t* G1    = (ushort_t*)(ws + 25165824);    // 49152*512 f16 = 50331648 B
    ushort_t* W0p   = (ushort_t*)(ws + 75497472);    // 114688 B
    ushort_t* W1p   = (ushort_t*)(ws + 75612160);    // 524288 B
    ushort_t* N0x   = (ushort_t*)(ws + 76136448);    // 270336 B
    ushort_t* N0m   = (ushort_t*)(ws + 76406784);    // 131072 B (L1 mfma pack)
    ushort_t* N1m   = (ushort_t*)(ws + 76537856);    // 262144 B (L2 mfma pack)

    pack_w<<<(1024 * 56 + 255) / 256, 256, 0, stream>>>(tWih0, 50, (const float*)0, 0, W0p, 1024, 56);
    pack_w<<<(1024 * 256 + 255) / 256, 256, 0, stream>>>(tWih1, 256, (const float*)0, 0, W1p, 1024, 256);
    pack_w<<<(512 * 264 + 255) / 256, 256, 0, stream>>>(nWih0, 257, (const float*)0, 0, N0x, 512, 264);
    pack_wmf<<<(512 * 128 + 255) / 256, 256, 0, stream>>>(nWhh0, 128, (const float*)0, 0, N0m, 128);
    pack_wmf<<<(512 * 256 + 255) / 256, 256, 0, stream>>>(nWih1, 128, nWhh1, 128, N1m, 256);

    phaseA<<<3072, 256, 0, stream>>>(note, W0p, tb0, W1p, tb1, feats);
    g1k<<<3072, 256, 0, stream>>>(feats, targ, N0x, nb0, G1);
    phaseB<<<64, 512, 0, stream>>>(G1, N0m, N1m, nb1, outW, outb, (float*)d_out);
}

// Round 6
// 386.694 us; speedup vs baseline: 2.2080x; 1.8272x over previous
//
#include <hip/hip_runtime.h>

typedef unsigned short ushort_t;
typedef unsigned int uint_t;
typedef _Float16 f16_t;
typedef _Float16 half2_t __attribute__((ext_vector_type(2)));
typedef _Float16 half8_t __attribute__((ext_vector_type(8)));
typedef float floatx4 __attribute__((ext_vector_type(4)));

__device__ __forceinline__ float dot2(uint_t w, uint_t x, float acc) {
    return __builtin_amdgcn_fdot2(__builtin_bit_cast(half2_t, w),
                                  __builtin_bit_cast(half2_t, x), acc, false);
}
__device__ __forceinline__ ushort_t f2h_bits(float f) {
    f16_t h = (f16_t)f;
    return __builtin_bit_cast(ushort_t, h);
}
__device__ __forceinline__ float h2f(ushort_t u) {
    return (float)__builtin_bit_cast(f16_t, u);
}
__device__ __forceinline__ float sigm(float x) { return 1.0f / (1.0f + __expf(-x)); }
__device__ __forceinline__ float tanhx(float x) {
    x = fminf(fmaxf(x, -15.0f), 15.0f);
    float e = __expf(2.0f * x);
    return (e - 1.0f) / (e + 1.0f);
}

// B-fragment layout used everywhere: frag(kt,q,n) at halves ((kt*4+q)*V + n)*8 + j,
// holding B[k][n] with k = kt*32 + q*8 + j. Consecutive n -> consecutive b128
// (coalesced global loads AND conflict-free LDS reads).
__device__ __forceinline__ half8_t ldfrag(const ushort_t* p, int V, int kt, int q, int n) {
    return *(const half8_t*)(p + ((size_t)((kt * 4 + q) * V + n)) * 8);
}

// generic pack: fp32 rows [V x KA|KB] -> f16 B-frags. srcA row stride = KA.
__global__ __launch_bounds__(256) void pack_frag(
    const float* __restrict__ srcA, int KA, const float* __restrict__ srcB, int KB,
    ushort_t* __restrict__ dst, int V, int K)
{
    int idx = blockIdx.x * 256 + threadIdx.x;
    if (idx >= V * K) return;
    int v = idx / K, k = idx - v * K;
    float val = 0.0f;
    if (k < KA) val = srcA[v * KA + k];
    else if (k < KA + KB) val = srcB[v * KB + (k - KA)];
    int kt = k >> 5, qq = (k >> 3) & 3, j = k & 7;
    dst[((size_t)((kt * 4 + qq) * V + v)) * 8 + j] = f2h_bits(val);
}

// t-LSTM pack (V=768): skip dead f-gate rows. v<256 -> i rows, 256..511 -> g
// (src rows 512..767), 512..767 -> o (src rows 768..1023). k >= Ksrc pads 0.
__global__ __launch_bounds__(256) void pack_tl(
    const float* __restrict__ src, int Ksrc, ushort_t* __restrict__ dst, int K)
{
    int idx = blockIdx.x * 256 + threadIdx.x;
    if (idx >= 768 * K) return;
    int v = idx / K, k = idx - v * K;
    int r = (v < 256) ? v : v + 256;
    float val = (k < Ksrc) ? src[r * Ksrc + k] : 0.0f;
    int kt = k >> 5, qq = (k >> 3) & 3, j = k & 7;
    dst[((size_t)((kt * 4 + qq) * 768 + v)) * 8 + j] = f2h_bits(val);
}

// fusedA: phaseA + g1k as one 3-GEMM MFMA kernel. 768 blocks x 64 rows.
// GEMM1: X[64x64] @ W0 -> gate -> H1[64x256] (LDS)
// GEMM2: H1 @ W1 -> gate -> H2[64x256] (LDS)
// GEMM3: H2 @ Wih0 (+ cond rank-1 + bias) -> G1[row,512] (global f16)
// Waves own unit-tiles => i/g/o accs in-lane => in-register elementwise.
__global__ __launch_bounds__(512, 2) void fusedA(
    const float* __restrict__ note, const float* __restrict__ targets,
    const ushort_t* __restrict__ W0m, const float* __restrict__ b0,
    const ushort_t* __restrict__ W1m, const float* __restrict__ b1,
    const ushort_t* __restrict__ N0x, const float* __restrict__ nWih0raw,
    const float* __restrict__ nb0,
    ushort_t* __restrict__ G1)
{
    __shared__ __align__(16) ushort_t xAa[64 * 64];
    __shared__ __align__(16) ushort_t xH1[64 * 256];
    __shared__ __align__(16) ushort_t xH2[64 * 256];
    const int tid = threadIdx.x;
    const int wv = tid >> 6, l = tid & 63, l16 = l & 15, q = l >> 4;
    const int r0A = blockIdx.x * 64;

    // features (pitch_pos | pitch_class | vicinity | chord), K padded 56->64
    for (int idx = tid; idx < 64 * 64; idx += 512) {
        int r = idx >> 6, c = idx & 63;
        int row = r0A + r;
        int b = row / 48, n = row - b * 48;
        float val = 0.0f;
        if (c == 0) val = (float)n * (1.0f / 48.0f);
        else if (c < 13) val = ((n % 12) == (c - 1)) ? 1.0f : 0.0f;
        else if (c < 38) {
            int p = n + (c - 13) - 12;
            if (p >= 0 && p < 48) val = note[b * 48 + p];
        } else if (c < 50) {
            const float* nb = note + b * 48 + (c - 38) * 4;
            val = nb[0] + nb[1] + nb[2] + nb[3];
        }
        int kb = c >> 3, j = c & 7;
        xAa[r * 64 + (((kb ^ r) & 7) << 3) + j] = f2h_bits(val);
    }
    __syncthreads();

    // ---- GEMM1 (K=64) + gate -> xH1 ----
#pragma unroll
    for (int s = 0; s < 2; ++s) {
        const int U = wv * 2 + s;
        const int u = U * 16 + l16;          // unit 0..255
        floatx4 acc[4][3] = {};
#pragma unroll
        for (int kt = 0; kt < 2; ++kt) {
            half8_t bI = ldfrag(W0m, 768, kt, q, u);
            half8_t bG = ldfrag(W0m, 768, kt, q, 256 + u);
            half8_t bO = ldfrag(W0m, 768, kt, q, 512 + u);
            int kbp = ((kt * 4 + q) ^ l16) & 7;
#pragma unroll
            for (int mt = 0; mt < 4; ++mt) {
                half8_t a = *(const half8_t*)&xAa[(mt * 16 + l16) * 64 + kbp * 8];
                acc[mt][0] = __builtin_amdgcn_mfma_f32_16x16x32_f16(a, bI, acc[mt][0], 0, 0, 0);
                acc[mt][1] = __builtin_amdgcn_mfma_f32_16x16x32_f16(a, bG, acc[mt][1], 0, 0, 0);
                acc[mt][2] = __builtin_amdgcn_mfma_f32_16x16x32_f16(a, bO, acc[mt][2], 0, 0, 0);
            }
        }
        float bi = b0[u], bg = b0[512 + u], bo = b0[768 + u];
        int kbW = u >> 3;   // 0..31
#pragma unroll
        for (int mt = 0; mt < 4; ++mt)
#pragma unroll
            for (int r = 0; r < 4; ++r) {
                float c = sigm(acc[mt][0][r] + bi) * tanhx(acc[mt][1][r] + bg);
                float h = sigm(acc[mt][2][r] + bo) * tanhx(c);
                int m = mt * 16 + q * 4 + r;
                int kbp = (kbW & 16) | ((kbW ^ (m & 15)) & 15);
                xH1[m * 256 + kbp * 8 + (u & 7)] = f2h_bits(h);
            }
    }
    __syncthreads();

    // ---- GEMM2 (K=256) + gate -> xH2 ----
#pragma unroll
    for (int s = 0; s < 2; ++s) {
        const int U = wv * 2 + s;
        const int u = U * 16 + l16;
        floatx4 acc[4][3] = {};
#pragma unroll
        for (int kt = 0; kt < 8; ++kt) {
            half8_t bI = ldfrag(W1m, 768, kt, q, u);
            half8_t bG = ldfrag(W1m, 768, kt, q, 256 + u);
            half8_t bO = ldfrag(W1m, 768, kt, q, 512 + u);
            int kb = kt * 4 + q;
            int kbp = (kb & 16) | ((kb ^ l16) & 15);
#pragma unroll
            for (int mt = 0; mt < 4; ++mt) {
                half8_t a = *(const half8_t*)&xH1[(mt * 16 + l16) * 256 + kbp * 8];
                acc[mt][0] = __builtin_amdgcn_mfma_f32_16x16x32_f16(a, bI, acc[mt][0], 0, 0, 0);
                acc[mt][1] = __builtin_amdgcn_mfma_f32_16x16x32_f16(a, bG, acc[mt][1], 0, 0, 0);
                acc[mt][2] = __builtin_amdgcn_mfma_f32_16x16x32_f16(a, bO, acc[mt][2], 0, 0, 0);
            }
        }
        float bi = b1[u], bg = b1[512 + u], bo = b1[768 + u];
        int kbW = u >> 3;
#pragma unroll
        for (int mt = 0; mt < 4; ++mt)
#pragma unroll
            for (int r = 0; r < 4; ++r) {
                float c = sigm(acc[mt][0][r] + bi) * tanhx(acc[mt][1][r] + bg);
                float h = sigm(acc[mt][2][r] + bo) * tanhx(c);
                int m = mt * 16 + q * 4 + r;
                int kbp = (kbW & 16) | ((kbW ^ (m & 15)) & 15);
                xH2[m * 256 + kbp * 8 + (u & 7)] = f2h_bits(h);
            }
    }
    __syncthreads();

    // ---- GEMM3 (K=256) + bias + cond rank-1 -> G1 ----
    {
        const int u2 = wv * 16 + l16;        // n-LSTM unit 0..127
        floatx4 acc[4][4] = {};              // [mt][gate i,f,g,o]
#pragma unroll
        for (int kt = 0; kt < 8; ++kt) {
            half8_t bf[4];
#pragma unroll
            for (int g = 0; g < 4; ++g) bf[g] = ldfrag(N0x, 512, kt, q, g * 128 + u2);
            int kb = kt * 4 + q;
            int kbp = (kb & 16) | ((kb ^ l16) & 15);
#pragma unroll
            for (int mt = 0; mt < 4; ++mt) {
                half8_t a = *(const half8_t*)&xH2[(mt * 16 + l16) * 256 + kbp * 8];
#pragma unroll
                for (int g = 0; g < 4; ++g)
                    acc[mt][g] = __builtin_amdgcn_mfma_f32_16x16x32_f16(a, bf[g], acc[mt][g], 0, 0, 0);
            }
        }
        float bias[4], wc[4];
#pragma unroll
        for (int g = 0; g < 4; ++g) {
            bias[g] = nb0[g * 128 + u2];
            wc[g] = nWih0raw[(size_t)(g * 128 + u2) * 257 + 256];
        }
#pragma unroll
        for (int mt = 0; mt < 4; ++mt) {
            float cond[4];
#pragma unroll
            for (int r = 0; r < 4; ++r) {
                int R = r0A + mt * 16 + q * 4 + r;
                cond[r] = (R % 48) ? targets[R - 1] : 0.0f;
            }
#pragma unroll
            for (int g = 0; g < 4; ++g)
#pragma unroll
                for (int r = 0; r < 4; ++r) {
                    int R = r0A + mt * 16 + q * 4 + r;
                    float val = acc[mt][g][r] + bias[g] + cond[r] * wc[g];
                    G1[(size_t)R * 512 + g * 128 + u2] = f2h_bits(val);
                }
        }
    }
}

// phaseB: 48-step 2-layer LSTM scan, 64 blocks x 16 batches, 8 waves = 8
// unit-tiles (in-register gating, c-states per lane). Whh0 B-frags in LDS;
// all 32 L2 B-frags loaded at step start; G1 register-prefetched 1 step ahead.
__global__ __launch_bounds__(512, 2) void phaseB(
    const ushort_t* __restrict__ G1, const ushort_t* __restrict__ N0m,
    const ushort_t* __restrict__ N1m, const float* __restrict__ nb1,
    const float* __restrict__ outW, const float* __restrict__ outb,
    float* __restrict__ out)
{
    __shared__ __align__(16) ushort_t w1s[4 * 4 * 512 * 8];  // 131072 B
    __shared__ __align__(16) ushort_t xA[16 * 256];          // [m][swz k]: k<128 h1, else h2
    __shared__ __align__(16) uint_t owp[64];
    const int tid = threadIdx.x;
    const int wv = tid >> 6, l = tid & 63, l16 = l & 15, q = l >> 4;
    const int r0 = blockIdx.x * 16;
    const int u = wv * 16 + l16;                 // unit 0..127

    for (int i = tid; i < 8192; i += 512) ((uint4*)w1s)[i] = ((const uint4*)N0m)[i];
    ((uint4*)xA)[tid] = make_uint4(0, 0, 0, 0);  // 512 uint4 = 8 kB
    if (tid < 64) {
        uint_t lo = f2h_bits(outW[2 * tid]);
        uint_t hi = f2h_bits(outW[2 * tid + 1]);
        owp[tid] = lo | (hi << 16);
    }
    const float bI = nb1[u], bF = nb1[128 + u], bG = nb1[256 + u], bO = nb1[384 + u];
    const float ob = outb[0];
    float c1[4] = {0, 0, 0, 0}, c2[4] = {0, 0, 0, 0};
    __syncthreads();

    // G1 prefetch for t=0
    ushort_t g1v[4][4];
#pragma unroll
    for (int g = 0; g < 4; ++g)
#pragma unroll
        for (int r = 0; r < 4; ++r)
            g1v[g][r] = G1[((size_t)(r0 + q * 4 + r) * 48) * 512 + g * 128 + u];

    for (int t = 0; t < 48; ++t) {
        // L2 B-frags: load all 32 now; consumed after 2 barriers (latency hidden)
        uint4 Bs[8][4];
#pragma unroll
        for (int kt = 0; kt < 8; ++kt)
#pragma unroll
            for (int g = 0; g < 4; ++g)
                Bs[kt][g] = *(const uint4*)(N1m + ((size_t)((kt * 4 + q) * 512 + g * 128 + u)) * 8);

        // L1 MFMA: gates = Whh0 @ h1(t-1), B from LDS
        floatx4 acc[4] = {};
#pragma unroll
        for (int kt = 0; kt < 4; ++kt) {
            int kbp = ((kt * 4 + q) ^ l16) & 15;
            half8_t a = *(const half8_t*)&xA[l16 * 256 + kbp * 8];
#pragma unroll
            for (int g = 0; g < 4; ++g) {
                half8_t bfr = *(const half8_t*)&w1s[((kt * 4 + q) * 512 + g * 128 + u) * 8];
                acc[g] = __builtin_amdgcn_mfma_f32_16x16x32_f16(a, bfr, acc[g], 0, 0, 0);
            }
        }
        __syncthreads();   // barA: all h1(t-1) reads done

        // L1 gate (in-register) + h1 write
        {
            int kbW = u >> 3;
#pragma unroll
            for (int r = 0; r < 4; ++r) {
                float gi = acc[0][r] + h2f(g1v[0][r]);
                float gf = acc[1][r] + h2f(g1v[1][r]);
                float gg = acc[2][r] + h2f(g1v[2][r]);
                float go = acc[3][r] + h2f(g1v[3][r]);
                c1[r] = sigm(gf) * c1[r] + sigm(gi) * tanhx(gg);
                float h1 = sigm(go) * tanhx(c1[r]);
                int m = q * 4 + r;
                xA[m * 256 + (((kbW ^ m) & 15) << 3) + (u & 7)] = f2h_bits(h1);
            }
        }
        // prefetch G1 for t+1 (whole next step to complete)
        {
            int tn = (t < 47) ? t + 1 : 47;
#pragma unroll
            for (int g = 0; g < 4; ++g)
#pragma unroll
                for (int r = 0; r < 4; ++r)
                    g1v[g][r] = G1[((size_t)(r0 + q * 4 + r) * 48 + tn) * 512 + g * 128 + u];
        }
        __syncthreads();   // barB: h1(t) visible

        // L2 MFMA: gates = W2 @ [h1(t); h2(t-1)], B from registers
        floatx4 acc2[4] = {};
#pragma unroll
        for (int kt = 0; kt < 8; ++kt) {
            int kb = kt * 4 + q;
            int kbp = (kb & 16) | ((kb ^ l16) & 15);
            half8_t a = *(const half8_t*)&xA[l16 * 256 + kbp * 8];
#pragma unroll
            for (int g = 0; g < 4; ++g)
                acc2[g] = __builtin_amdgcn_mfma_f32_16x16x32_f16(
                    a, __builtin_bit_cast(half8_t, Bs[kt][g]), acc2[g], 0, 0, 0);
        }
        __syncthreads();   // barC: all h2(t-1) reads done

        // L2 gate + h2 write
        {
            int kbW = u >> 3;
#pragma unroll
            for (int r = 0; r < 4; ++r) {
                float gi = acc2[0][r] + bI;
                float gf = acc2[1][r] + bF;
                float gg = acc2[2][r] + bG;
                float go = acc2[3][r] + bO;
                c2[r] = sigm(gf) * c2[r] + sigm(gi) * tanhx(gg);
                float h2 = sigm(go) * tanhx(c2[r]);
                int m = q * 4 + r;
                xA[m * 256 + ((16 | ((kbW ^ m) & 15)) << 3) + (u & 7)] = f2h_bits(h2);
            }
        }
        __syncthreads();   // barD: h2(t) visible

        // output head: 32 lanes per batch row, dot2 + shuffle reduce
        {
            int m = tid >> 5, hl = tid & 31;
            int kbp = 16 | (((hl >> 1) ^ m) & 15);
            uint2 xv = *(const uint2*)&xA[m * 256 + kbp * 8 + (hl & 1) * 4];
            float p = dot2(owp[hl * 2], xv.x, 0.0f);
            p = dot2(owp[hl * 2 + 1], xv.y, p);
#pragma unroll
            for (int off = 16; off > 0; off >>= 1) p += __shfl_down(p, off, 32);
            if (hl == 0) out[(r0 + m) * 48 + t] = sigm(p + ob);
        }
    }
}

extern "C" void kernel_launch(void* const* d_in, const int* in_sizes, int n_in,
                              void* d_out, int out_size, void* d_ws, size_t ws_size,
                              hipStream_t stream)
{
    const float* note  = (const float*)d_in[0];
    const float* targ  = (const float*)d_in[1];
    const float* tWih0 = (const float*)d_in[2];
    const float* tb0   = (const float*)d_in[4];
    const float* tWih1 = (const float*)d_in[5];
    const float* tb1   = (const float*)d_in[7];
    const float* nWih0 = (const float*)d_in[8];
    const float* nWhh0 = (const float*)d_in[9];
    const float* nb0   = (const float*)d_in[10];
    const float* nWih1 = (const float*)d_in[11];
    const float* nWhh1 = (const float*)d_in[12];
    const float* nb1   = (const float*)d_in[13];
    const float* outW  = (const float*)d_in[14];
    const float* outb  = (const float*)d_in[15];

    char* ws = (char*)d_ws;
    ushort_t* G1  = (ushort_t*)(ws);              // 49152*512*2 = 50331648 B
    ushort_t* W0m = (ushort_t*)(ws + 50331648);   // 2*4*768*8*2  =  98304 B
    ushort_t* W1m = (ushort_t*)(ws + 50429952);   // 8*4*768*8*2  = 393216 B
    ushort_t* N0x = (ushort_t*)(ws + 50823168);   // 8*4*512*8*2  = 262144 B
    ushort_t* N0m = (ushort_t*)(ws + 51085312);   // 4*4*512*8*2  = 131072 B
    ushort_t* N1m = (ushort_t*)(ws + 51216384);   // 8*4*512*8*2  = 262144 B

    pack_tl<<<192, 256, 0, stream>>>(tWih0, 50, W0m, 64);
    pack_tl<<<768, 256, 0, stream>>>(tWih1, 256, W1m, 256);
    pack_frag<<<512, 256, 0, stream>>>(nWih0, 257, (const float*)0, 0, N0x, 512, 256);
    pack_frag<<<256, 256, 0, stream>>>(nWhh0, 128, (const float*)0, 0, N0m, 512, 128);
    pack_frag<<<512, 256, 0, stream>>>(nWih1, 128, nWhh1, 128, N1m, 512, 256);

    fusedA<<<768, 512, 0, stream>>>(note, targ, W0m, tb0, W1m, tb1, N0x, nWih0, nb0, G1);
    phaseB<<<64, 512, 0, stream>>>(G1, N0m, N1m, nb1, outW, outb, (float*)d_out);
}

// Round 7
// 380.159 us; speedup vs baseline: 2.2459x; 1.0172x over previous
//
#include <hip/hip_runtime.h>

typedef unsigned short ushort_t;
typedef unsigned int uint_t;
typedef _Float16 f16_t;
typedef _Float16 half2_t __attribute__((ext_vector_type(2)));
typedef _Float16 half8_t __attribute__((ext_vector_type(8)));
typedef float floatx4 __attribute__((ext_vector_type(4)));

__device__ __forceinline__ ushort_t f2h_bits(float f) {
    f16_t h = (f16_t)f;
    return __builtin_bit_cast(ushort_t, h);
}
__device__ __forceinline__ float h2f(ushort_t u) {
    return (float)__builtin_bit_cast(f16_t, u);
}
__device__ __forceinline__ float sigm(float x) { return 1.0f / (1.0f + __expf(-x)); }
__device__ __forceinline__ float tanhx(float x) {
    x = fminf(fmaxf(x, -15.0f), 15.0f);
    float e = __expf(2.0f * x);
    return (e - 1.0f) / (e + 1.0f);
}

// B-fragment layout everywhere: frag(kt,q,n) at halves ((kt*4+q)*V + n)*8 + j,
// holding B[k][n] with k = kt*32 + q*8 + j. Consecutive n -> contiguous b128.
__device__ __forceinline__ half8_t ldfrag(const ushort_t* p, int V, int kt, int q, int n) {
    return *(const half8_t*)(p + ((size_t)((kt * 4 + q) * V + n)) * 8);
}

// generic pack: fp32 rows [V x KA|KB] -> f16 B-frags.
__global__ __launch_bounds__(256) void pack_frag(
    const float* __restrict__ srcA, int KA, const float* __restrict__ srcB, int KB,
    ushort_t* __restrict__ dst, int V, int K)
{
    int idx = blockIdx.x * 256 + threadIdx.x;
    if (idx >= V * K) return;
    int v = idx / K, k = idx - v * K;
    float val = 0.0f;
    if (k < KA) val = srcA[v * KA + k];
    else if (k < KA + KB) val = srcB[v * KB + (k - KA)];
    int kt = k >> 5, qq = (k >> 3) & 3, j = k & 7;
    dst[((size_t)((kt * 4 + qq) * V + v)) * 8 + j] = f2h_bits(val);
}

// t-LSTM pack (V=768): skip dead f-gate rows. v<256 -> i rows, 256..511 -> g
// (src rows 512..767), 512..767 -> o (src rows 768..1023). k >= Ksrc pads 0.
__global__ __launch_bounds__(256) void pack_tl(
    const float* __restrict__ src, int Ksrc, ushort_t* __restrict__ dst, int K)
{
    int idx = blockIdx.x * 256 + threadIdx.x;
    if (idx >= 768 * K) return;
    int v = idx / K, k = idx - v * K;
    int r = (v < 256) ? v : v + 256;
    float val = (k < Ksrc) ? src[r * Ksrc + k] : 0.0f;
    int kt = k >> 5, qq = (k >> 3) & 3, j = k & 7;
    dst[((size_t)((kt * 4 + qq) * 768 + v)) * 8 + j] = f2h_bits(val);
}

// fusedA: 3-GEMM MFMA kernel. 768 blocks x 64 rows.
// GEMM1: X[64x64]@W0 -> gate -> H1; GEMM2: H1@W1 -> gate -> H2;
// GEMM3: H2@Wih0 (+cond rank-1 +bias) -> G1[row,512].
__global__ __launch_bounds__(512, 2) void fusedA(
    const float* __restrict__ note, const float* __restrict__ targets,
    const ushort_t* __restrict__ W0m, const float* __restrict__ b0,
    const ushort_t* __restrict__ W1m, const float* __restrict__ b1,
    const ushort_t* __restrict__ N0x, const float* __restrict__ nWih0raw,
    const float* __restrict__ nb0,
    ushort_t* __restrict__ G1)
{
    __shared__ __align__(16) ushort_t xAa[64 * 64];
    __shared__ __align__(16) ushort_t xH1[64 * 256];
    __shared__ __align__(16) ushort_t xH2[64 * 256];
    const int tid = threadIdx.x;
    const int wv = tid >> 6, l = tid & 63, l16 = l & 15, q = l >> 4;
    const int r0A = blockIdx.x * 64;

    for (int idx = tid; idx < 64 * 64; idx += 512) {
        int r = idx >> 6, c = idx & 63;
        int row = r0A + r;
        int b = row / 48, n = row - b * 48;
        float val = 0.0f;
        if (c == 0) val = (float)n * (1.0f / 48.0f);
        else if (c < 13) val = ((n % 12) == (c - 1)) ? 1.0f : 0.0f;
        else if (c < 38) {
            int p = n + (c - 13) - 12;
            if (p >= 0 && p < 48) val = note[b * 48 + p];
        } else if (c < 50) {
            const float* nb = note + b * 48 + (c - 38) * 4;
            val = nb[0] + nb[1] + nb[2] + nb[3];
        }
        int kb = c >> 3, j = c & 7;
        xAa[r * 64 + (((kb ^ r) & 7) << 3) + j] = f2h_bits(val);
    }
    __syncthreads();

    // ---- GEMM1 (K=64) + gate -> xH1 ----
#pragma unroll
    for (int s = 0; s < 2; ++s) {
        const int U = wv * 2 + s;
        const int u = U * 16 + l16;
        floatx4 acc[4][3] = {};
#pragma unroll
        for (int kt = 0; kt < 2; ++kt) {
            half8_t bI = ldfrag(W0m, 768, kt, q, u);
            half8_t bG = ldfrag(W0m, 768, kt, q, 256 + u);
            half8_t bO = ldfrag(W0m, 768, kt, q, 512 + u);
            int kbp = ((kt * 4 + q) ^ l16) & 7;
#pragma unroll
            for (int mt = 0; mt < 4; ++mt) {
                half8_t a = *(const half8_t*)&xAa[(mt * 16 + l16) * 64 + kbp * 8];
                acc[mt][0] = __builtin_amdgcn_mfma_f32_16x16x32_f16(a, bI, acc[mt][0], 0, 0, 0);
                acc[mt][1] = __builtin_amdgcn_mfma_f32_16x16x32_f16(a, bG, acc[mt][1], 0, 0, 0);
                acc[mt][2] = __builtin_amdgcn_mfma_f32_16x16x32_f16(a, bO, acc[mt][2], 0, 0, 0);
            }
        }
        float bi = b0[u], bg = b0[512 + u], bo = b0[768 + u];
        int kbW = u >> 3;
#pragma unroll
        for (int mt = 0; mt < 4; ++mt)
#pragma unroll
            for (int r = 0; r < 4; ++r) {
                float c = sigm(acc[mt][0][r] + bi) * tanhx(acc[mt][1][r] + bg);
                float h = sigm(acc[mt][2][r] + bo) * tanhx(c);
                int m = mt * 16 + q * 4 + r;
                int kbp = (kbW & 16) | ((kbW ^ (m & 15)) & 15);
                xH1[m * 256 + kbp * 8 + (u & 7)] = f2h_bits(h);
            }
    }
    __syncthreads();

    // ---- GEMM2 (K=256) + gate -> xH2 ----
#pragma unroll
    for (int s = 0; s < 2; ++s) {
        const int U = wv * 2 + s;
        const int u = U * 16 + l16;
        floatx4 acc[4][3] = {};
#pragma unroll
        for (int kt = 0; kt < 8; ++kt) {
            half8_t bI = ldfrag(W1m, 768, kt, q, u);
            half8_t bG = ldfrag(W1m, 768, kt, q, 256 + u);
            half8_t bO = ldfrag(W1m, 768, kt, q, 512 + u);
            int kb = kt * 4 + q;
            int kbp = (kb & 16) | ((kb ^ l16) & 15);
#pragma unroll
            for (int mt = 0; mt < 4; ++mt) {
                half8_t a = *(const half8_t*)&xH1[(mt * 16 + l16) * 256 + kbp * 8];
                acc[mt][0] = __builtin_amdgcn_mfma_f32_16x16x32_f16(a, bI, acc[mt][0], 0, 0, 0);
                acc[mt][1] = __builtin_amdgcn_mfma_f32_16x16x32_f16(a, bG, acc[mt][1], 0, 0, 0);
                acc[mt][2] = __builtin_amdgcn_mfma_f32_16x16x32_f16(a, bO, acc[mt][2], 0, 0, 0);
            }
        }
        float bi = b1[u], bg = b1[512 + u], bo = b1[768 + u];
        int kbW = u >> 3;
#pragma unroll
        for (int mt = 0; mt < 4; ++mt)
#pragma unroll
            for (int r = 0; r < 4; ++r) {
                float c = sigm(acc[mt][0][r] + bi) * tanhx(acc[mt][1][r] + bg);
                float h = sigm(acc[mt][2][r] + bo) * tanhx(c);
                int m = mt * 16 + q * 4 + r;
                int kbp = (kbW & 16) | ((kbW ^ (m & 15)) & 15);
                xH2[m * 256 + kbp * 8 + (u & 7)] = f2h_bits(h);
            }
    }
    __syncthreads();

    // ---- GEMM3 (K=256) + bias + cond rank-1 -> G1 ----
    {
        const int u2 = wv * 16 + l16;
        floatx4 acc[4][4] = {};
#pragma unroll
        for (int kt = 0; kt < 8; ++kt) {
            half8_t bf[4];
#pragma unroll
            for (int g = 0; g < 4; ++g) bf[g] = ldfrag(N0x, 512, kt, q, g * 128 + u2);
            int kb = kt * 4 + q;
            int kbp = (kb & 16) | ((kb ^ l16) & 15);
#pragma unroll
            for (int mt = 0; mt < 4; ++mt) {
                half8_t a = *(const half8_t*)&xH2[(mt * 16 + l16) * 256 + kbp * 8];
#pragma unroll
                for (int g = 0; g < 4; ++g)
                    acc[mt][g] = __builtin_amdgcn_mfma_f32_16x16x32_f16(a, bf[g], acc[mt][g], 0, 0, 0);
            }
        }
        float bias[4], wc[4];
#pragma unroll
        for (int g = 0; g < 4; ++g) {
            bias[g] = nb0[g * 128 + u2];
            wc[g] = nWih0raw[(size_t)(g * 128 + u2) * 257 + 256];
        }
#pragma unroll
        for (int mt = 0; mt < 4; ++mt) {
            float cond[4];
#pragma unroll
            for (int r = 0; r < 4; ++r) {
                int R = r0A + mt * 16 + q * 4 + r;
                cond[r] = (R % 48) ? targets[R - 1] : 0.0f;
            }
#pragma unroll
            for (int g = 0; g < 4; ++g)
#pragma unroll
                for (int r = 0; r < 4; ++r) {
                    int R = r0A + mt * 16 + q * 4 + r;
                    float val = acc[mt][g][r] + bias[g] + cond[r] * wc[g];
                    G1[(size_t)R * 512 + g * 128 + u2] = f2h_bits(val);
                }
        }
    }
}

// phaseB: 48-step 2-layer LSTM scan, 64 blocks x 16 batches, 8 waves = 8
// unit-tiles. All weights on-chip: Whh0 B-frags in LDS, L2-layer B-frags in
// persistent registers (128 VGPRs). Double-buffered h1/h2 -> 2 barriers/step.
// Output head reduced from registers (shfl + tiny LDS combine).
__global__ __launch_bounds__(512, 2) void phaseB(
    const ushort_t* __restrict__ G1, const ushort_t* __restrict__ N0m,
    const ushort_t* __restrict__ N1m, const float* __restrict__ nb1,
    const float* __restrict__ outW, const float* __restrict__ outb,
    float* __restrict__ out)
{
    __shared__ __align__(16) ushort_t w1s[16 * 512 * 8];  // 131072 B
    __shared__ __align__(16) ushort_t xA[16 * 512];       // [m][k]: h1 b0|h1 b1|h2 b0|h2 b1
    __shared__ __align__(16) float ghead[8][16];
    const int tid = threadIdx.x;
    const int wv = tid >> 6, l = tid & 63, l16 = l & 15, q = l >> 4;
    const int r0 = blockIdx.x * 16;
    const int u = wv * 16 + l16;                 // unit 0..127

    for (int i = tid; i < 8192; i += 512) ((uint4*)w1s)[i] = ((const uint4*)N0m)[i];
    for (int i = tid; i < 1024; i += 512) ((uint4*)xA)[i] = make_uint4(0, 0, 0, 0);

    // persistent L2-layer B-frags: this wave's 64-gate column slice
    uint4 B2[8][4];
#pragma unroll
    for (int kt = 0; kt < 8; ++kt)
#pragma unroll
        for (int g = 0; g < 4; ++g)
            B2[kt][g] = *(const uint4*)(N1m + ((size_t)((kt * 4 + q) * 512 + g * 128 + u)) * 8);

    const float bI = nb1[u], bF = nb1[128 + u], bG = nb1[256 + u], bO = nb1[384 + u];
    const float ob = outb[0];
    const float owf = outW[u];
    float c1[4] = {0, 0, 0, 0}, c2[4] = {0, 0, 0, 0};

    // G1 for t=0
    ushort_t g1v[4][4];
#pragma unroll
    for (int g = 0; g < 4; ++g)
#pragma unroll
        for (int r = 0; r < 4; ++r)
            g1v[g][r] = G1[((size_t)(r0 + q * 4 + r) * 48) * 512 + g * 128 + u];
    __syncthreads();

    const int kbW = u >> 3;
    const int jW = u & 7;

    for (int t = 0; t < 48; ++t) {
        const int cur = (t & 1) * 128;
        const int prv = ((t & 1) ^ 1) * 128;

        // L1 MFMA: gates = Whh0 @ h1(t-1); A from xA h1[prv], B from LDS
        floatx4 acc[4] = {};
#pragma unroll
        for (int kt = 0; kt < 4; ++kt) {
            int kb = kt * 4 + q;
            int kbp = kb ^ (l16 & 7);
            half8_t a = *(const half8_t*)&xA[l16 * 512 + prv + kbp * 8];
#pragma unroll
            for (int g = 0; g < 4; ++g) {
                half8_t bfr = *(const half8_t*)&w1s[((kt * 4 + q) * 512 + g * 128 + u) * 8];
                acc[g] = __builtin_amdgcn_mfma_f32_16x16x32_f16(a, bfr, acc[g], 0, 0, 0);
            }
        }
        // E1: gate + write h1(t) into buf cur (no barrier needed before this:
        // writes go to the opposite buffer from concurrent reads)
#pragma unroll
        for (int r = 0; r < 4; ++r) {
            float gi = acc[0][r] + h2f(g1v[0][r]);
            float gf = acc[1][r] + h2f(g1v[1][r]);
            float gg = acc[2][r] + h2f(g1v[2][r]);
            float go = acc[3][r] + h2f(g1v[3][r]);
            c1[r] = sigm(gf) * c1[r] + sigm(gi) * tanhx(gg);
            float h1 = sigm(go) * tanhx(c1[r]);
            int m = q * 4 + r;
            xA[m * 512 + cur + (((kbW ^ (m & 7)) & 15) << 3) + jW] = f2h_bits(h1);
        }
        __syncthreads();   // #1: h1(t) visible

        // G1 prefetch for t+1: issued here so the vmcnt(0) drain at barrier #2
        // has the whole L2-MFMA + E2 phase as its latency window
        {
            int tn = (t < 47) ? t + 1 : 47;
#pragma unroll
            for (int g = 0; g < 4; ++g)
#pragma unroll
                for (int r = 0; r < 4; ++r)
                    g1v[g][r] = G1[((size_t)(r0 + q * 4 + r) * 48 + tn) * 512 + g * 128 + u];
        }

        // L2 MFMA: gates = W2 @ [h1(t); h2(t-1)]; B from registers only
        floatx4 acc2[4] = {};
#pragma unroll
        for (int kt = 0; kt < 8; ++kt) {
            int base = (kt < 4) ? cur : (256 + prv);
            int kbr = (kt & 3) * 4 + q;
            int kbp = kbr ^ (l16 & 7);
            half8_t a = *(const half8_t*)&xA[l16 * 512 + base + kbp * 8];
#pragma unroll
            for (int g = 0; g < 4; ++g)
                acc2[g] = __builtin_amdgcn_mfma_f32_16x16x32_f16(
                    a, __builtin_bit_cast(half8_t, B2[kt][g]), acc2[g], 0, 0, 0);
        }
        // E2: gate + write h2(t) buf cur + head partial from registers
        float p[4];
#pragma unroll
        for (int r = 0; r < 4; ++r) {
            float gi = acc2[0][r] + bI;
            float gf = acc2[1][r] + bF;
            float gg = acc2[2][r] + bG;
            float go = acc2[3][r] + bO;
            c2[r] = sigm(gf) * c2[r] + sigm(gi) * tanhx(gg);
            float h2 = sigm(go) * tanhx(c2[r]);
            int m = q * 4 + r;
            xA[m * 512 + 256 + cur + (((kbW ^ (m & 7)) & 15) << 3) + jW] = f2h_bits(h2);
            p[r] = h2 * owf;
        }
#pragma unroll
        for (int mask = 1; mask < 16; mask <<= 1)
#pragma unroll
            for (int r = 0; r < 4; ++r) p[r] += __shfl_xor(p[r], mask, 64);
        if (l16 == 0) {
#pragma unroll
            for (int r = 0; r < 4; ++r) ghead[wv][q * 4 + r] = p[r];
        }
        __syncthreads();   // #2: h2(t) + ghead visible

        if (tid < 16) {
            float s = 0.0f;
#pragma unroll
            for (int w = 0; w < 8; ++w) s += ghead[w][tid];
            out[(r0 + tid) * 48 + t] = sigm(s + ob);
        }
    }
}

extern "C" void kernel_launch(void* const* d_in, const int* in_sizes, int n_in,
                              void* d_out, int out_size, void* d_ws, size_t ws_size,
                              hipStream_t stream)
{
    const float* note  = (const float*)d_in[0];
    const float* targ  = (const float*)d_in[1];
    const float* tWih0 = (const float*)d_in[2];
    const float* tb0   = (const float*)d_in[4];
    const float* tWih1 = (const float*)d_in[5];
    const float* tb1   = (const float*)d_in[7];
    const float* nWih0 = (const float*)d_in[8];
    const float* nWhh0 = (const float*)d_in[9];
    const float* nb0   = (const float*)d_in[10];
    const float* nWih1 = (const float*)d_in[11];
    const float* nWhh1 = (const float*)d_in[12];
    const float* nb1   = (const float*)d_in[13];
    const float* outW  = (const float*)d_in[14];
    const float* outb  = (const float*)d_in[15];

    char* ws = (char*)d_ws;
    ushort_t* G1  = (ushort_t*)(ws);              // 49152*512*2 = 50331648 B
    ushort_t* W0m = (ushort_t*)(ws + 50331648);   //  98304 B
    ushort_t* W1m = (ushort_t*)(ws + 50429952);   // 393216 B
    ushort_t* N0x = (ushort_t*)(ws + 50823168);   // 262144 B
    ushort_t* N0m = (ushort_t*)(ws + 51085312);   // 131072 B
    ushort_t* N1m = (ushort_t*)(ws + 51216384);   // 262144 B

    pack_tl<<<192, 256, 0, stream>>>(tWih0, 50, W0m, 64);
    pack_tl<<<768, 256, 0, stream>>>(tWih1, 256, W1m, 256);
    pack_frag<<<512, 256, 0, stream>>>(nWih0, 257, (const float*)0, 0, N0x, 512, 256);
    pack_frag<<<256, 256, 0, stream>>>(nWhh0, 128, (const float*)0, 0, N0m, 512, 128);
    pack_frag<<<512, 256, 0, stream>>>(nWih1, 128, nWhh1, 128, N1m, 512, 256);

    fusedA<<<768, 512, 0, stream>>>(note, targ, W0m, tb0, W1m, tb1, N0x, nWih0, nb0, G1);
    phaseB<<<64, 512, 0, stream>>>(G1, N0m, N1m, nb1, outW, outb, (float*)d_out);
}